// Round 5
// baseline (2946.080 us; speedup 1.0000x reference)
//
#include <hip/hip_runtime.h>
#include <cstdint>
#include <cstddef>

#define Tt  512
#define Kk  8
#define NI  256
#define UN  256
#define G4  1024   // 4*UN

typedef unsigned short ushort_t;
typedef __attribute__((ext_vector_type(8))) short short8;
typedef __attribute__((ext_vector_type(4))) float f32x4;

__global__ void zero_ws(unsigned int* p, int n) {
    int stride = gridDim.x * blockDim.x;
    for (int i = blockIdx.x * blockDim.x + threadIdx.x; i < n; i += stride)
        p[i] = 0u;
}

__device__ __forceinline__ ushort_t f2bf(float x) {
    union { float f; unsigned int u; } v; v.f = x;
    unsigned int r = v.u + 0x7FFFu + ((v.u >> 16) & 1u);
    return (ushort_t)(r >> 16);
}

__device__ __forceinline__ unsigned pack2bf(float a, float b) {
    return (unsigned)f2bf(a) | ((unsigned)f2bf(b) << 16);
}

__device__ __forceinline__ float hsig(float z) {
    return fminf(1.0f, fmaxf(0.0f, fmaf(z, 0.2f, 0.5f)));
}

__device__ __forceinline__ float fast_tanh(float x) {
    float e = __expf(2.0f * x);
    return 1.0f - 2.0f * __builtin_amdgcn_rcpf(e + 1.0f);
}

// ---------------- Phase A: xw[t'][b*8+k][col] = bias + x@W (fp32, proven) ----------------
__global__ __launch_bounds__(256) void xw_gemm(const float* __restrict__ x,
                                               const float* __restrict__ W,
                                               const float* __restrict__ bias,
                                               float* __restrict__ xw, int t0) {
    __shared__ __align__(16) float At[16][132];
    __shared__ __align__(16) float Bt[16][132];

    const int k  = blockIdx.z;
    const int C0 = blockIdx.x * 128;
    const int R0 = blockIdx.y * 128;
    const int tid = threadIdx.x;
    const int tx = tid & 15, ty = tid >> 4;

    float acc[8][8];
#pragma unroll
    for (int i = 0; i < 8; i++)
#pragma unroll
        for (int j = 0; j < 8; j++) acc[i][j] = 0.0f;

    const int lakk = tid & 15, larl = tid >> 4;
    const int lbc  = tid & 127, lbk = tid >> 7;

    for (int kt = 0; kt < NI; kt += 16) {
#pragma unroll
        for (int ps = 0; ps < 8; ps++) {
            int rloc = larl + ps * 16;
            int r = R0 + rloc;
            int b = r & 15, tp = r >> 4;
            At[lakk][rloc] = x[(((size_t)b * Tt + (t0 + tp)) * Kk + k) * NI + kt + lakk];
        }
#pragma unroll
        for (int ps = 0; ps < 8; ps++) {
            int kkr = lbk + ps * 2;
            Bt[kkr][lbc] = W[((size_t)k * NI + kt + kkr) * G4 + C0 + lbc];
        }
        __syncthreads();
#pragma unroll
        for (int kk = 0; kk < 16; kk++) {
            const float4* Ar = (const float4*)&At[kk][ty * 8];
            const float4* Br = (const float4*)&Bt[kk][tx * 8];
            float4 a0 = Ar[0], a1 = Ar[1];
            float4 b0 = Br[0], b1 = Br[1];
            float a[8] = {a0.x, a0.y, a0.z, a0.w, a1.x, a1.y, a1.z, a1.w};
            float bb[8] = {b0.x, b0.y, b0.z, b0.w, b1.x, b1.y, b1.z, b1.w};
#pragma unroll
            for (int i = 0; i < 8; i++)
#pragma unroll
                for (int j = 0; j < 8; j++)
                    acc[i][j] = fmaf(a[i], bb[j], acc[i][j]);
        }
        __syncthreads();
    }
    float bv[8];
#pragma unroll
    for (int j = 0; j < 8; j++) bv[j] = bias[(size_t)k * G4 + C0 + tx * 8 + j];
#pragma unroll
    for (int i = 0; i < 8; i++) {
        int r = R0 + ty * 8 + i;
        int b = r & 15, tp = r >> 4;
        float* op = xw + ((size_t)tp * 128 + b * 8 + k) * G4 + C0 + tx * 8;
#pragma unroll
        for (int j = 0; j < 8; j++) op[j] = acc[i][j] + bv[j];
    }
}

// ---------------- Phase B: relaxed-atomic exchange (no wbl2/inv in the loop) ----------------
// 32 wgs x 256 thr: k=bid&7, uq=bid>>3 owns units [uq*64,uq*64+64). wave w = gate w.
// bfr: 128 VGPR/lane of U slice. Exchange: relaxed agent atomics only.
__global__ __launch_bounds__(256, 1) void lstm_mfma4(
    const float* __restrict__ xw,        // [TC][128][1024]
    const float* __restrict__ U,
    float* __restrict__ out,
    ushort_t* __restrict__ hstate,       // [8][16][256] bf16
    float* __restrict__ cstate,          // [32][1024]
    unsigned* __restrict__ hbuf32,       // [2][8][16][128] u32 (bf16 unit-pairs)
    int* __restrict__ arrive,            // [t*8+k], counts waves (16 = ready)
    int t0, int TC) {
    const int tid  = threadIdx.x;
    const int lane = tid & 63;
    const int w    = tid >> 6;        // gate
    const int k    = blockIdx.x & 7;
    const int uq   = blockIdx.x >> 3; // 0..3
    const int l15  = lane & 15, quad = lane >> 4;
    const int colw = w * 256 + uq * 64;

    __shared__ __align__(16) ushort_t hfr[8 * 64 * 8];   // A-frag layout, 8KB
    __shared__ float gact[4][16][65];

    // preload B-fragments of U slice (bf16): 128 VGPRs/lane
    short8 bfr[4][8];
    const size_t Ub = (size_t)k * (NI * G4);
#pragma unroll
    for (int c = 0; c < 4; c++) {
        const int col = colw + c * 16 + l15;
#pragma unroll
        for (int q = 0; q < 8; q++) {
            short8 v;
#pragma unroll
            for (int j = 0; j < 8; j++)
                v[j] = (short)f2bf(U[Ub + (size_t)(q * 32 + quad * 8 + j) * G4 + col]);
            bfr[c][q] = v;
        }
    }

    // c/h ownership: thread -> unit-pair up (units 2up,2up+1), batches bb and bb+8
    const int up = tid & 31;
    const int bb = tid >> 5;          // 0..7
    float cc[4];                      // [pair p][unit e]: c[bb+8p][2up+e]
    const size_t cb = ((size_t)(k * 4 + uq)) * 1024 + (size_t)tid * 4;
#pragma unroll
    for (int r = 0; r < 4; r++) cc[r] = cstate[cb + r];

    // initial h scatter: hstate[k][b][unit] -> A-frag LDS (16B load + b128 write)
#pragma unroll
    for (int i = 0; i < 2; i++) {
        int idx = tid + 256 * i;
        int b = idx & 15, c8 = idx >> 4;      // c8 0..31
        short8 hv = *(const short8*)&hstate[(size_t)k * 4096 + b * 256 + c8 * 8];
        *(short8*)&hfr[(((c8 >> 2) * 64) + b + 16 * (c8 & 3)) * 8] = hv;
    }
    __syncthreads();

    // xw for t=0
    float xwv[4][4];
#pragma unroll
    for (int c = 0; c < 4; c++)
#pragma unroll
        for (int r = 0; r < 4; r++)
            xwv[c][r] = xw[((size_t)0 * 128 + (quad * 4 + r) * 8 + k) * G4 + colw + c * 16 + l15];

#pragma unroll 1
    for (int t = 0; t < TC; t++) {
        const int g = t0 + t;

        // z_hU = h @ Uslice via MFMA
        f32x4 acc[4];
        const f32x4 zv = {0.f, 0.f, 0.f, 0.f};
#pragma unroll
        for (int c = 0; c < 4; c++) acc[c] = zv;
#pragma unroll
        for (int q = 0; q < 8; q++) {
            short8 af = *(const short8*)&hfr[(q * 64 + lane) * 8];
#pragma unroll
            for (int c = 0; c < 4; c++)
                acc[c] = __builtin_amdgcn_mfma_f32_16x16x32_bf16(af, bfr[c][q], acc[c], 0, 0, 0);
        }

        // prefetch xw for t+1 (overlaps with MFMA drain / activation)
        float xwn[4][4];
        if (t + 1 < TC) {
#pragma unroll
            for (int c = 0; c < 4; c++)
#pragma unroll
                for (int r = 0; r < 4; r++)
                    xwn[c][r] = xw[((size_t)(t + 1) * 128 + (quad * 4 + r) * 8 + k) * G4 + colw + c * 16 + l15];
        }

        // gate activation (wave w = gate w) -> LDS
#pragma unroll
        for (int c = 0; c < 4; c++)
#pragma unroll
            for (int r = 0; r < 4; r++) {
                float z = acc[c][r] + xwv[c][r];
                float a = (w == 0) ? fast_tanh(z) : hsig(z);
                gact[w][quad * 4 + r][c * 16 + l15] = a;
            }
        __syncthreads();   // S1: gact visible, hfr reads done

        // c/h update: thread owns (bb, bb+8) x units (2up, 2up+1)
        float hn[4];
#pragma unroll
        for (int p = 0; p < 2; p++) {
            int b = bb + 8 * p;
#pragma unroll
            for (int e = 0; e < 2; e++) {
                int ul = 2 * up + e;
                float av = gact[0][b][ul], iv = gact[1][b][ul];
                float fv = gact[2][b][ul], ov = gact[3][b][ul];
                float cn = av * iv + fv * cc[p * 2 + e];
                cc[p * 2 + e] = cn;
                hn[p * 2 + e] = ov * fast_tanh(cn);
            }
        }

        if (t + 1 < TC) {
            const int par = (g + 1) & 1;
            unsigned* hb = hbuf32 + ((size_t)par * 8 + k) * 2048;
            // publish own h (packed bf16 pairs) via RELAXED agent atomics (-> MALL, no wbl2)
            __hip_atomic_store(&hb[bb * 128 + uq * 32 + up], pack2bf(hn[0], hn[1]),
                               __ATOMIC_RELAXED, __HIP_MEMORY_SCOPE_AGENT);
            __hip_atomic_store(&hb[(bb + 8) * 128 + uq * 32 + up], pack2bf(hn[2], hn[3]),
                               __ATOMIC_RELAXED, __HIP_MEMORY_SCOPE_AGENT);
            // out stores (plain; drained by the same vmcnt below)
            {
                float2 v0 = {hn[0], hn[1]}, v1 = {hn[2], hn[3]};
                *(float2*)&out[(((size_t)bb * Tt + g) * Kk + k) * UN + uq * 64 + 2 * up] = v0;
                *(float2*)&out[(((size_t)(bb + 8) * Tt + g) * Kk + k) * UN + uq * 64 + 2 * up] = v1;
            }
            __asm__ volatile("s_waitcnt vmcnt(0)" ::: "memory");   // own-wave stores at MALL
            if (lane == 0)
                __hip_atomic_fetch_add(&arrive[(g + 1) * 8 + k], 1,
                                       __ATOMIC_RELAXED, __HIP_MEMORY_SCOPE_AGENT);
            // all threads poll (relaxed load: no buffer_inv)
            while (__hip_atomic_load(&arrive[(g + 1) * 8 + k],
                                     __ATOMIC_RELAXED, __HIP_MEMORY_SCOPE_AGENT) < 16) {}
            // reload full h_{t+1}: 8 relaxed u32 loads -> short8 -> ds_write_b128
#pragma unroll
            for (int i = 0; i < 2; i++) {
                int idx = tid + 256 * i;
                int b = idx & 15, c8 = idx >> 4;
                unsigned d[4];
#pragma unroll
                for (int j = 0; j < 4; j++)
                    d[j] = __hip_atomic_load(&hb[b * 128 + c8 * 4 + j],
                                             __ATOMIC_RELAXED, __HIP_MEMORY_SCOPE_AGENT);
                short8 hv;
#pragma unroll
                for (int j = 0; j < 4; j++) {
                    hv[2 * j]     = (short)(d[j] & 0xFFFFu);
                    hv[2 * j + 1] = (short)(d[j] >> 16);
                }
                *(short8*)&hfr[(((c8 >> 2) * 64) + b + 16 * (c8 & 3)) * 8] = hv;
            }
            __syncthreads();   // S2: hfr ready
#pragma unroll
            for (int c = 0; c < 4; c++)
#pragma unroll
                for (int r = 0; r < 4; r++) xwv[c][r] = xwn[c][r];
        } else {
            // last step of chunk: out + persist state (plain ops; kernel end drains)
            float2 v0 = {hn[0], hn[1]}, v1 = {hn[2], hn[3]};
            *(float2*)&out[(((size_t)bb * Tt + g) * Kk + k) * UN + uq * 64 + 2 * up] = v0;
            *(float2*)&out[(((size_t)(bb + 8) * Tt + g) * Kk + k) * UN + uq * 64 + 2 * up] = v1;
            unsigned* hs32 = (unsigned*)hstate;
            hs32[(size_t)k * 2048 + bb * 128 + uq * 32 + up] = pack2bf(hn[0], hn[1]);
            hs32[(size_t)k * 2048 + (bb + 8) * 128 + uq * 32 + up] = pack2bf(hn[2], hn[3]);
#pragma unroll
            for (int r = 0; r < 4; r++) cstate[cb + r] = cc[r];
        }
    }
}

extern "C" void kernel_launch(void* const* d_in, const int* in_sizes, int n_in,
                              void* d_out, int out_size, void* d_ws, size_t ws_size,
                              hipStream_t stream) {
    const float* x    = (const float*)d_in[0];
    const float* W    = (const float*)d_in[1];
    const float* U    = (const float*)d_in[2];
    const float* bias = (const float*)d_in[3];
    float* out = (float*)d_out;

    // tail: cstate 128KB | hstate 64KB | hbuf 128KB | arrive 64KB (16KB used)
    const size_t TAIL = 131072 + 65536 + 131072 + 65536;  // 393216 B
    int TC = 16;
    const int cands[6] = {512, 256, 128, 64, 32, 16};
    for (int ci = 0; ci < 6; ci++) {
        size_t need = (size_t)cands[ci] * 128 * 1024 * 4 + TAIL;
        if (need <= ws_size) { TC = cands[ci]; break; }
    }

    float* xw = (float*)d_ws;
    char* p = (char*)d_ws + (size_t)TC * 128 * 1024 * 4;
    float*    cstate = (float*)p;     p += 131072;
    ushort_t* hstate = (ushort_t*)p;  p += 65536;
    unsigned* hbuf32 = (unsigned*)p;  p += 131072;
    int*      arrive = (int*)p;

    zero_ws<<<dim3(128), dim3(256), 0, stream>>>((unsigned int*)cstate, (int)(TAIL / 4));

    for (int t0 = 0; t0 < Tt; t0 += TC) {
        xw_gemm<<<dim3(G4 / 128, TC * 16 / 128, Kk), dim3(256), 0, stream>>>(
            x, W, bias, xw, t0);
        lstm_mfma4<<<dim3(32), dim3(256), 0, stream>>>(
            xw, U, out, hstate, cstate, hbuf32, arrive, t0, TC);
    }
}